// Round 2
// baseline (226.966 us; speedup 1.0000x reference)
//
#include <hip/hip_runtime.h>
#include <math.h>

#define NCAPS 8
#define SEQ 200
#define EMB 128
#define CDIM 64
#define NROUNDS 3
#define BPAD 68    // sBeh row pad (floats): 68%32=4 -> conflict-free row-stride reads
#define APAD 132   // sA row pad: 528B rows, 16B-aligned float4
#define CH 64      // projection chunk rows
#define CPAD 68    // sCaps row pad

__device__ __forceinline__ float4 ld4(const float* p) { return *reinterpret_cast<const float4*>(p); }
__device__ __forceinline__ void st4(float* p, float4 v) { *reinterpret_cast<float4*>(p) = v; }

__global__ __launch_bounds__(256) void mie_kernel(
    const float* __restrict__ behaviors,      // [B][200][128]
    const unsigned char* __restrict__ maskraw, // bool bytes OR int32 OR float32 (detected)
    const float* __restrict__ S,              // [128][64]
    const float* __restrict__ B0,             // [8][200]
    float* __restrict__ out)                  // [B][8][64]
{
  __shared__ float sA[CH][APAD];        // 33.8 KB
  __shared__ float sBeh[SEQ][BPAD];     // 54.4 KB
  __shared__ float sB[NCAPS][SEQ];      // 6.4 KB
  __shared__ float sWt[SEQ][NCAPS];     // 6.4 KB  (W transposed: [l][k])
  __shared__ float sCaps[NCAPS][CPAD];  // 2.2 KB
  __shared__ float sPart[4][NCAPS][CDIM]; // 8 KB
  __shared__ float sMask[SEQ];          // 0.8 KB
  __shared__ int sFlagA, sFlagB;

  const int b = blockIdx.x;
  const int t = threadIdx.x;
  const int lane = t & 63;
  const int w = t >> 6;

  // ---- detect mask dtype over first 1KB ----
  // int32 0/1: bytes at off%4!=0 all zero.
  // bool bytes: nonzero bytes at off%4==1 (w.h.p. within 256 samples).
  // float32 0.0/1.0: nonzero only at off%4==2,3 (0x3F80).
  if (t == 0) { sFlagA = 0; sFlagB = 0; }
  __syncthreads();
  for (int i = t; i < 1024; i += 256) {
    unsigned char v = maskraw[i];
    if (v != 0) {
      int m = i & 3;
      if (m == 1) atomicOr(&sFlagA, 1);
      else if (m >= 2) atomicOr(&sFlagB, 1);
    }
  }
  __syncthreads();
  const int mode = sFlagA ? 1 : (sFlagB ? 2 : 0);  // 1=bytes, 2=float32, 0=int32

  // ---- load mask (as 0/1 float) and B0 ----
  if (mode == 1) {
    for (int i = t; i < SEQ; i += 256)
      sMask[i] = maskraw[(size_t)b * SEQ + i] ? 1.0f : 0.0f;
  } else if (mode == 2) {
    const float* mf = (const float*)maskraw;
    for (int i = t; i < SEQ; i += 256)
      sMask[i] = (mf[(size_t)b * SEQ + i] != 0.0f) ? 1.0f : 0.0f;
  } else {
    const int* mi = (const int*)maskraw;
    for (int i = t; i < SEQ; i += 256)
      sMask[i] = mi[(size_t)b * SEQ + i] ? 1.0f : 0.0f;
  }
  for (int i = t; i < NCAPS * SEQ; i += 256)
    (&sB[0][0])[i] = B0[i];

  // ---- projection: beh = behaviors[b] @ S  (200x128 . 128x64) ----
  const int tx = t & 15, ty = t >> 4;
  const int d0 = tx * 4;
  for (int l0 = 0; l0 < SEQ; l0 += CH) {
    const int R = (SEQ - l0 < CH) ? (SEQ - l0) : CH;
    __syncthreads();  // protect sA from previous chunk's readers
    for (int idx = t; idx < R * 32; idx += 256) {
      int r = idx >> 5, c = (idx & 31) * 4;
      st4(&sA[r][c], ld4(behaviors + ((size_t)b * SEQ + l0 + r) * EMB + c));
    }
    __syncthreads();
    float4 acc[4];
#pragma unroll
    for (int j = 0; j < 4; ++j) acc[j] = make_float4(0.f, 0.f, 0.f, 0.f);
#pragma unroll 2
    for (int e0 = 0; e0 < EMB; e0 += 4) {
      float4 s0 = ld4(S + (size_t)(e0 + 0) * CDIM + d0);
      float4 s1 = ld4(S + (size_t)(e0 + 1) * CDIM + d0);
      float4 s2 = ld4(S + (size_t)(e0 + 2) * CDIM + d0);
      float4 s3 = ld4(S + (size_t)(e0 + 3) * CDIM + d0);
#pragma unroll
      for (int j = 0; j < 4; ++j) {
        int r = ty + 16 * j;
        if (r < R) {
          float4 a = ld4(&sA[r][e0]);
          acc[j].x = fmaf(a.x, s0.x, acc[j].x); acc[j].y = fmaf(a.x, s0.y, acc[j].y);
          acc[j].z = fmaf(a.x, s0.z, acc[j].z); acc[j].w = fmaf(a.x, s0.w, acc[j].w);
          acc[j].x = fmaf(a.y, s1.x, acc[j].x); acc[j].y = fmaf(a.y, s1.y, acc[j].y);
          acc[j].z = fmaf(a.y, s1.z, acc[j].z); acc[j].w = fmaf(a.y, s1.w, acc[j].w);
          acc[j].x = fmaf(a.z, s2.x, acc[j].x); acc[j].y = fmaf(a.z, s2.y, acc[j].y);
          acc[j].z = fmaf(a.z, s2.z, acc[j].z); acc[j].w = fmaf(a.z, s2.w, acc[j].w);
          acc[j].x = fmaf(a.w, s3.x, acc[j].x); acc[j].y = fmaf(a.w, s3.y, acc[j].y);
          acc[j].z = fmaf(a.w, s3.z, acc[j].z); acc[j].w = fmaf(a.w, s3.w, acc[j].w);
        }
      }
    }
#pragma unroll
    for (int j = 0; j < 4; ++j) {
      int r = ty + 16 * j;
      if (r < R) st4(&sBeh[l0 + r][d0], acc[j]);
    }
  }
  __syncthreads();

  // ---- routing rounds ----
  for (int round = 0; round < NROUNDS; ++round) {
    // Phase A: masked softmax over l for rows k=w and k=w+4 (one wave per row)
#pragma unroll
    for (int kk = 0; kk < 2; ++kk) {
      const int k = w + kk * 4;
      float v0 = sB[k][lane],       f0 = sMask[lane];
      float v1 = sB[k][lane + 64],  f1 = sMask[lane + 64];
      float v2 = sB[k][lane + 128], f2 = sMask[lane + 128];
      float v3 = 0.f, f3 = 0.f;
      if (lane < SEQ - 192) { v3 = sB[k][lane + 192]; f3 = sMask[lane + 192]; }
      float m = -3.402823466e38f;
      if (f0 > 0.f) m = fmaxf(m, v0);
      if (f1 > 0.f) m = fmaxf(m, v1);
      if (f2 > 0.f) m = fmaxf(m, v2);
      if (f3 > 0.f) m = fmaxf(m, v3);
#pragma unroll
      for (int off = 32; off >= 1; off >>= 1) m = fmaxf(m, __shfl_xor(m, off));
      float e0 = (f0 > 0.f) ? __expf(v0 - m) : 0.f;
      float e1 = (f1 > 0.f) ? __expf(v1 - m) : 0.f;
      float e2 = (f2 > 0.f) ? __expf(v2 - m) : 0.f;
      float e3 = (f3 > 0.f) ? __expf(v3 - m) : 0.f;
      float s = ((e0 + e1) + (e2 + e3));
#pragma unroll
      for (int off = 32; off >= 1; off >>= 1) s += __shfl_xor(s, off);
      float inv = (s > 0.f) ? (1.0f / s) : 0.f;
      sWt[lane][k] = e0 * inv;
      sWt[lane + 64][k] = e1 * inv;
      sWt[lane + 128][k] = e2 * inv;
      if (lane < SEQ - 192) sWt[lane + 192][k] = e3 * inv;
    }
    __syncthreads();

    // Phase B: caps_raw[k][d] = sum_l W[k][l]*beh[l][d]
    {
      const int dg = t & 15, lp = t >> 4;
      float4 ck[8];
#pragma unroll
      for (int k = 0; k < 8; ++k) ck[k] = make_float4(0.f, 0.f, 0.f, 0.f);
      for (int l = lp; l < SEQ; l += 16) {
        float4 b4 = ld4(&sBeh[l][dg * 4]);
        float4 wa = ld4(&sWt[l][0]);
        float4 wb = ld4(&sWt[l][4]);
        ck[0].x = fmaf(wa.x, b4.x, ck[0].x); ck[0].y = fmaf(wa.x, b4.y, ck[0].y);
        ck[0].z = fmaf(wa.x, b4.z, ck[0].z); ck[0].w = fmaf(wa.x, b4.w, ck[0].w);
        ck[1].x = fmaf(wa.y, b4.x, ck[1].x); ck[1].y = fmaf(wa.y, b4.y, ck[1].y);
        ck[1].z = fmaf(wa.y, b4.z, ck[1].z); ck[1].w = fmaf(wa.y, b4.w, ck[1].w);
        ck[2].x = fmaf(wa.z, b4.x, ck[2].x); ck[2].y = fmaf(wa.z, b4.y, ck[2].y);
        ck[2].z = fmaf(wa.z, b4.z, ck[2].z); ck[2].w = fmaf(wa.z, b4.w, ck[2].w);
        ck[3].x = fmaf(wa.w, b4.x, ck[3].x); ck[3].y = fmaf(wa.w, b4.y, ck[3].y);
        ck[3].z = fmaf(wa.w, b4.z, ck[3].z); ck[3].w = fmaf(wa.w, b4.w, ck[3].w);
        ck[4].x = fmaf(wb.x, b4.x, ck[4].x); ck[4].y = fmaf(wb.x, b4.y, ck[4].y);
        ck[4].z = fmaf(wb.x, b4.z, ck[4].z); ck[4].w = fmaf(wb.x, b4.w, ck[4].w);
        ck[5].x = fmaf(wb.y, b4.x, ck[5].x); ck[5].y = fmaf(wb.y, b4.y, ck[5].y);
        ck[5].z = fmaf(wb.y, b4.z, ck[5].z); ck[5].w = fmaf(wb.y, b4.w, ck[5].w);
        ck[6].x = fmaf(wb.z, b4.x, ck[6].x); ck[6].y = fmaf(wb.z, b4.y, ck[6].y);
        ck[6].z = fmaf(wb.z, b4.z, ck[6].z); ck[6].w = fmaf(wb.z, b4.w, ck[6].w);
        ck[7].x = fmaf(wb.w, b4.x, ck[7].x); ck[7].y = fmaf(wb.w, b4.y, ck[7].y);
        ck[7].z = fmaf(wb.w, b4.z, ck[7].z); ck[7].w = fmaf(wb.w, b4.w, ck[7].w);
      }
      // reduce over the 4 l-partitions inside this wave (lane bits 4,5)
#pragma unroll
      for (int off = 16; off <= 32; off <<= 1) {
#pragma unroll
        for (int k = 0; k < 8; ++k) {
          ck[k].x += __shfl_xor(ck[k].x, off);
          ck[k].y += __shfl_xor(ck[k].y, off);
          ck[k].z += __shfl_xor(ck[k].z, off);
          ck[k].w += __shfl_xor(ck[k].w, off);
        }
      }
      if (lane < 16) {
#pragma unroll
        for (int k = 0; k < 8; ++k) st4(&sPart[w][k][lane * 4], ck[k]);
      }
    }
    __syncthreads();
    // BUGFIX (round 1): 512 cells, 256 threads -> each thread must do TWO.
    for (int i = t; i < NCAPS * CDIM; i += 256) {
      int k = i >> 6, d = i & 63;
      sCaps[k][d] = (sPart[0][k][d] + sPart[1][k][d]) + (sPart[2][k][d] + sPart[3][k][d]);
    }
    __syncthreads();

    // Phase C: squash + (last round) output
#pragma unroll
    for (int kk = 0; kk < 2; ++kk) {
      const int k = w + kk * 4;
      float v = sCaps[k][lane];
      float q = v * v;
#pragma unroll
      for (int off = 32; off >= 1; off >>= 1) q += __shfl_xor(q, off);
      float n = sqrtf(q);
      float f = (q > 0.f) ? (q / ((1.0f + q) * n)) : 0.f;
      v *= f;
      sCaps[k][lane] = v;
      if (round == NROUNDS - 1)
        out[((size_t)b * NCAPS + k) * CDIM + lane] = v;
    }
    __syncthreads();

    // Phase D: B[k][l] += dot(caps[k], beh[l])
    if (round < NROUNDS - 1) {
      const int k = t & 7;
      float4 cp[16];
#pragma unroll
      for (int i = 0; i < 16; ++i) cp[i] = ld4(&sCaps[k][i * 4]);
      for (int oi = t; oi < NCAPS * SEQ; oi += 256) {
        int l = oi >> 3;
        float px = 0.f, py = 0.f, pz = 0.f, pw = 0.f;
#pragma unroll
        for (int i = 0; i < 16; ++i) {
          float4 b4 = ld4(&sBeh[l][i * 4]);
          px = fmaf(cp[i].x, b4.x, px);
          py = fmaf(cp[i].y, b4.y, py);
          pz = fmaf(cp[i].z, b4.z, pz);
          pw = fmaf(cp[i].w, b4.w, pw);
        }
        sB[k][l] += (px + py) + (pz + pw);
      }
    }
    __syncthreads();
  }
}

extern "C" void kernel_launch(void* const* d_in, const int* in_sizes, int n_in,
                              void* d_out, int out_size, void* d_ws, size_t ws_size,
                              hipStream_t stream) {
  const float* behaviors = (const float*)d_in[0];
  const unsigned char* maskraw = (const unsigned char*)d_in[1];
  const float* S = (const float*)d_in[2];
  const float* B0 = (const float*)d_in[3];
  float* out = (float*)d_out;
  const int B = in_sizes[0] / (SEQ * EMB);
  mie_kernel<<<dim3(B), dim3(256), 0, stream>>>(behaviors, maskraw, S, B0, out);
}

// Round 3
// 117.891 us; speedup vs baseline: 1.9252x; 1.9252x over previous
//
#include <hip/hip_runtime.h>
#include <math.h>

#define NCAPS 8
#define SEQ 200
#define EMB 128
#define CDIM 64
#define NROUNDS 3
#define NT 512
#define BPAD 68    // sBeh row pad (floats): breaks power-of-2 strides
#define CPAD 68

__device__ __forceinline__ float4 ld4(const float* p) { return *reinterpret_cast<const float4*>(p); }
__device__ __forceinline__ void st4(float* p, float4 v) { *reinterpret_cast<float4*>(p) = v; }

__global__ __launch_bounds__(NT, 4) void mie_kernel(
    const float* __restrict__ behaviors,      // [B][200][128]
    const unsigned char* __restrict__ maskraw, // bool bytes OR int32 OR float32 (detected)
    const float* __restrict__ S,              // [128][64]
    const float* __restrict__ B0,             // [8][200]
    float* __restrict__ out)                  // [B][8][64]
{
  __shared__ float sBeh[SEQ][BPAD];     // 54.4 KB
  __shared__ float sB[NCAPS][SEQ];      // 6.4 KB
  __shared__ float sW[NCAPS][SEQ];      // 6.4 KB  (k-major: wave w broadcasts row w)
  __shared__ float sCaps[NCAPS][CPAD];  // 2.2 KB
  __shared__ float sMask[SEQ];          // 0.8 KB
  __shared__ int sFlagA, sFlagB;
  // total ~68.5 KB -> 2 blocks/CU; 8 waves/block -> 16 waves/CU

  const int b = blockIdx.x;
  const int t = threadIdx.x;
  const int lane = t & 63;
  const int w = t >> 6;

  // ---- detect mask dtype over first 1KB ----
  // int32 0/1: bytes at off%4!=0 all zero.
  // bool bytes: nonzero bytes appear at off%4==1 (w.h.p.).
  // float32 0.0/1.0: nonzero only at off%4==2,3 (0x3F80).
  if (t == 0) { sFlagA = 0; sFlagB = 0; }
  __syncthreads();
  for (int i = t; i < 1024; i += NT) {
    unsigned char v = maskraw[i];
    if (v != 0) {
      int m = i & 3;
      if (m == 1) atomicOr(&sFlagA, 1);
      else if (m >= 2) atomicOr(&sFlagB, 1);
    }
  }
  __syncthreads();
  const int mode = sFlagA ? 1 : (sFlagB ? 2 : 0);  // 1=bytes, 2=float32, 0=int32

  // ---- load mask (as 0/1 float) and B0 ----
  if (mode == 1) {
    for (int i = t; i < SEQ; i += NT)
      sMask[i] = maskraw[(size_t)b * SEQ + i] ? 1.0f : 0.0f;
  } else if (mode == 2) {
    const float* mf = (const float*)maskraw;
    for (int i = t; i < SEQ; i += NT)
      sMask[i] = (mf[(size_t)b * SEQ + i] != 0.0f) ? 1.0f : 0.0f;
  } else {
    const int* mi = (const int*)maskraw;
    for (int i = t; i < SEQ; i += NT)
      sMask[i] = mi[(size_t)b * SEQ + i] ? 1.0f : 0.0f;
  }
  for (int i = t; i < NCAPS * SEQ; i += NT)
    (&sB[0][0])[i] = B0[i];

  // ---- projection: sBeh = behaviors[b] @ S  (200x128 . 128x64) ----
  // 16x32 thread grid: tx -> 4 dims of d, ty -> rows ty+32j (j=0..6).
  // A read straight from global (read-once; 16 lanes share an address -> L1
  // broadcast). S is 32KB, L1-resident after first touch.
  {
    const int tx = t & 15, ty = t >> 4;
    const int d0 = tx * 4;
    const float* Arow = behaviors + (size_t)b * SEQ * EMB;
    float4 acc[7];
#pragma unroll
    for (int j = 0; j < 7; ++j) acc[j] = make_float4(0.f, 0.f, 0.f, 0.f);
    for (int e0 = 0; e0 < EMB; e0 += 4) {
      float4 s0 = ld4(S + (size_t)(e0 + 0) * CDIM + d0);
      float4 s1 = ld4(S + (size_t)(e0 + 1) * CDIM + d0);
      float4 s2 = ld4(S + (size_t)(e0 + 2) * CDIM + d0);
      float4 s3 = ld4(S + (size_t)(e0 + 3) * CDIM + d0);
#pragma unroll
      for (int j = 0; j < 7; ++j) {
        const int r = ty + 32 * j;
        if (r < SEQ) {
          float4 a = ld4(Arow + (size_t)r * EMB + e0);
          acc[j].x = fmaf(a.x, s0.x, acc[j].x); acc[j].y = fmaf(a.x, s0.y, acc[j].y);
          acc[j].z = fmaf(a.x, s0.z, acc[j].z); acc[j].w = fmaf(a.x, s0.w, acc[j].w);
          acc[j].x = fmaf(a.y, s1.x, acc[j].x); acc[j].y = fmaf(a.y, s1.y, acc[j].y);
          acc[j].z = fmaf(a.y, s1.z, acc[j].z); acc[j].w = fmaf(a.y, s1.w, acc[j].w);
          acc[j].x = fmaf(a.z, s2.x, acc[j].x); acc[j].y = fmaf(a.z, s2.y, acc[j].y);
          acc[j].z = fmaf(a.z, s2.z, acc[j].z); acc[j].w = fmaf(a.z, s2.w, acc[j].w);
          acc[j].x = fmaf(a.w, s3.x, acc[j].x); acc[j].y = fmaf(a.w, s3.y, acc[j].y);
          acc[j].z = fmaf(a.w, s3.z, acc[j].z); acc[j].w = fmaf(a.w, s3.w, acc[j].w);
        }
      }
    }
#pragma unroll
    for (int j = 0; j < 7; ++j) {
      const int r = ty + 32 * j;
      if (r < SEQ) st4(&sBeh[r][d0], acc[j]);
    }
  }
  __syncthreads();

  // ---- routing rounds ----
  for (int round = 0; round < NROUNDS; ++round) {
    // Phase A: masked softmax over l; wave w owns capsule k=w.
    {
      const int k = w;
      float v0 = sB[k][lane],       f0 = sMask[lane];
      float v1 = sB[k][lane + 64],  f1 = sMask[lane + 64];
      float v2 = sB[k][lane + 128], f2 = sMask[lane + 128];
      float v3 = 0.f, f3 = 0.f;
      if (lane < SEQ - 192) { v3 = sB[k][lane + 192]; f3 = sMask[lane + 192]; }
      float m = -3.402823466e38f;
      if (f0 > 0.f) m = fmaxf(m, v0);
      if (f1 > 0.f) m = fmaxf(m, v1);
      if (f2 > 0.f) m = fmaxf(m, v2);
      if (f3 > 0.f) m = fmaxf(m, v3);
#pragma unroll
      for (int off = 32; off >= 1; off >>= 1) m = fmaxf(m, __shfl_xor(m, off));
      float e0 = (f0 > 0.f) ? __expf(v0 - m) : 0.f;
      float e1 = (f1 > 0.f) ? __expf(v1 - m) : 0.f;
      float e2 = (f2 > 0.f) ? __expf(v2 - m) : 0.f;
      float e3 = (f3 > 0.f) ? __expf(v3 - m) : 0.f;
      float s = ((e0 + e1) + (e2 + e3));
#pragma unroll
      for (int off = 32; off >= 1; off >>= 1) s += __shfl_xor(s, off);
      float inv = (s > 0.f) ? (1.0f / s) : 0.f;
      sW[k][lane] = e0 * inv;
      sW[k][lane + 64] = e1 * inv;
      sW[k][lane + 128] = e2 * inv;
      if (lane < SEQ - 192) sW[k][lane + 192] = e3 * inv;
    }
    __syncthreads();

    // Phase B + squash: wave w owns k=w, lane owns d=lane.
    // caps[w][lane] = sum_l W[w][l] * beh[l][lane]  -- W broadcast (same addr
    // across wave, free), beh row-consecutive (2 lanes/bank = free).
    {
      float a0 = 0.f, a1 = 0.f, a2 = 0.f, a3 = 0.f;
#pragma unroll 2
      for (int l = 0; l < SEQ; l += 4) {
        a0 = fmaf(sW[w][l + 0], sBeh[l + 0][lane], a0);
        a1 = fmaf(sW[w][l + 1], sBeh[l + 1][lane], a1);
        a2 = fmaf(sW[w][l + 2], sBeh[l + 2][lane], a2);
        a3 = fmaf(sW[w][l + 3], sBeh[l + 3][lane], a3);
      }
      float v = (a0 + a1) + (a2 + a3);
      // squash: full-wave reduce of v^2 over d
      float q = v * v;
#pragma unroll
      for (int off = 32; off >= 1; off >>= 1) q += __shfl_xor(q, off);
      float n = sqrtf(q);
      float f = (q > 0.f) ? (q / ((1.0f + q) * n)) : 0.f;
      v *= f;
      sCaps[w][lane] = v;
      if (round == NROUNDS - 1)
        out[((size_t)b * NCAPS + w) * CDIM + lane] = v;
    }
    __syncthreads();

    // Phase D: B[k][l] += dot(caps[k], beh[l]).  k = t&7, l strided by 64.
    if (round < NROUNDS - 1) {
      const int k = t & 7;
      float4 cp[16];
#pragma unroll
      for (int i = 0; i < 16; ++i) cp[i] = ld4(&sCaps[k][i * 4]);
      for (int oi = t; oi < NCAPS * SEQ; oi += NT) {
        int l = oi >> 3;
        float px = 0.f, py = 0.f, pz = 0.f, pw = 0.f;
#pragma unroll
        for (int i = 0; i < 16; ++i) {
          float4 b4 = ld4(&sBeh[l][i * 4]);
          px = fmaf(cp[i].x, b4.x, px);
          py = fmaf(cp[i].y, b4.y, py);
          pz = fmaf(cp[i].z, b4.z, pz);
          pw = fmaf(cp[i].w, b4.w, pw);
        }
        sB[k][l] += (px + py) + (pz + pw);
      }
    }
    __syncthreads();
  }
}

extern "C" void kernel_launch(void* const* d_in, const int* in_sizes, int n_in,
                              void* d_out, int out_size, void* d_ws, size_t ws_size,
                              hipStream_t stream) {
  const float* behaviors = (const float*)d_in[0];
  const unsigned char* maskraw = (const unsigned char*)d_in[1];
  const float* S = (const float*)d_in[2];
  const float* B0 = (const float*)d_in[3];
  float* out = (float*)d_out;
  const int B = in_sizes[0] / (SEQ * EMB);
  mie_kernel<<<dim3(B), dim3(NT), 0, stream>>>(behaviors, maskraw, S, B0, out);
}

// Round 4
// 91.668 us; speedup vs baseline: 2.4759x; 1.2861x over previous
//
#include <hip/hip_runtime.h>
#include <math.h>

#define NCAPS 8
#define SEQ 200
#define EMB 128
#define CDIM 64
#define NROUNDS 3
#define NT 512
#define BPAD 68    // sBeh row pad (floats): 272B rows -> Phase D 8-row b128 reads spread banks
#define CPAD 68

typedef __bf16 bf16x8 __attribute__((ext_vector_type(8)));
typedef float f32x4 __attribute__((ext_vector_type(4)));
typedef unsigned short ushort8 __attribute__((ext_vector_type(8)));

__device__ __forceinline__ float4 ld4(const float* p) { return *reinterpret_cast<const float4*>(p); }
__device__ __forceinline__ void st4(float* p, float4 v) { *reinterpret_cast<float4*>(p) = v; }

// RNE float -> bf16 bits
__device__ __forceinline__ unsigned short f2bf(float v) {
  unsigned u = __builtin_bit_cast(unsigned, v);
  u += 0x7FFFu + ((u >> 16) & 1u);
  return (unsigned short)(u >> 16);
}
__device__ __forceinline__ float bf2f(unsigned short b) {
  unsigned u = ((unsigned)b) << 16;
  return __builtin_bit_cast(float, u);
}

__global__ __launch_bounds__(NT, 2) void mie_kernel(
    const float* __restrict__ behaviors,      // [B][200][128]
    const unsigned char* __restrict__ maskraw, // bool bytes OR int32 OR float32 (detected)
    const float* __restrict__ S,              // [128][64]
    const float* __restrict__ B0,             // [8][200]
    float* __restrict__ out)                  // [B][8][64]
{
  __shared__ float sBeh[SEQ][BPAD];     // 54.4 KB (fp32 projection output)
  __shared__ ushort8 sSfH[16][64];      // 16 KB: S hi fragments, [(ks*4+ct)][lane]
  __shared__ ushort8 sSfL[16][64];      // 16 KB: S lo fragments
  __shared__ float sB[NCAPS][SEQ];      // 6.4 KB
  __shared__ float sW[NCAPS][SEQ];      // 6.4 KB
  __shared__ float sCaps[NCAPS][CPAD];  // 2.2 KB
  __shared__ float sMask[SEQ];          // 0.8 KB
  __shared__ int sFlagA, sFlagB;
  // total ~102.4 KB -> 1 block/CU, 8 waves

  const int b = blockIdx.x;
  const int t = threadIdx.x;
  const int lane = t & 63;
  const int w = t >> 6;

  // ---- detect mask dtype over first 1KB ----
  if (t == 0) { sFlagA = 0; sFlagB = 0; }
  __syncthreads();
  for (int i = t; i < 1024; i += NT) {
    unsigned char v = maskraw[i];
    if (v != 0) {
      int m = i & 3;
      if (m == 1) atomicOr(&sFlagA, 1);
      else if (m >= 2) atomicOr(&sFlagB, 1);
    }
  }
  __syncthreads();
  const int mode = sFlagA ? 1 : (sFlagB ? 2 : 0);  // 1=bytes, 2=float32, 0=int32

  // ---- load mask, B0, and stage split-bf16 S fragments ----
  if (mode == 1) {
    for (int i = t; i < SEQ; i += NT)
      sMask[i] = maskraw[(size_t)b * SEQ + i] ? 1.0f : 0.0f;
  } else if (mode == 2) {
    const float* mf = (const float*)maskraw;
    for (int i = t; i < SEQ; i += NT)
      sMask[i] = (mf[(size_t)b * SEQ + i] != 0.0f) ? 1.0f : 0.0f;
  } else {
    const int* mi = (const int*)maskraw;
    for (int i = t; i < SEQ; i += NT)
      sMask[i] = mi[(size_t)b * SEQ + i] ? 1.0f : 0.0f;
  }
  for (int i = t; i < NCAPS * SEQ; i += NT)
    (&sB[0][0])[i] = B0[i];

  // S fragment staging: element (e,d) -> frag[(e>>5)*4 + (d>>4)][ (((e>>3)&3)<<4) + (d&15) ][ e&7 ]
  for (int i = t; i < EMB * CDIM; i += NT) {
    int e = i >> 6, d = i & 63;
    float v = S[i];
    unsigned short h = f2bf(v);
    unsigned short lo = f2bf(v - bf2f(h));
    int fi = (e >> 5) * 4 + (d >> 4);
    int ln = (((e >> 3) & 3) << 4) + (d & 15);
    int j = e & 7;
    ((unsigned short*)&sSfH[fi][ln])[j] = h;
    ((unsigned short*)&sSfL[fi][ln])[j] = lo;
  }
  __syncthreads();

  // ---- projection via MFMA: sBeh = behaviors[b] @ S  (split-bf16, 3 terms) ----
  // 13 row-tiles of 16; wave w takes rt = w, w+8. 4 col-tiles of 16. K = 4 steps of 32.
  {
    const int fr = lane & 15;   // A row-in-tile; also C col-in-tile
    const int kg = lane >> 4;   // k-group (0..3)
    for (int rt = w; rt < 13; rt += 8) {
      const int r0 = rt * 16;
      const int row = r0 + fr;
      bf16x8 aH[4], aL[4];
#pragma unroll
      for (int ks = 0; ks < 4; ++ks) {
        float a[8];
        if (row < SEQ) {
          const float* p = behaviors + ((size_t)b * SEQ + row) * EMB + ks * 32 + kg * 8;
          float4 u0 = ld4(p), u1 = ld4(p + 4);
          a[0] = u0.x; a[1] = u0.y; a[2] = u0.z; a[3] = u0.w;
          a[4] = u1.x; a[5] = u1.y; a[6] = u1.z; a[7] = u1.w;
        } else {
#pragma unroll
          for (int j = 0; j < 8; ++j) a[j] = 0.f;
        }
        ushort8 h, lo;
#pragma unroll
        for (int j = 0; j < 8; ++j) {
          unsigned short hh = f2bf(a[j]);
          h[j] = hh;
          lo[j] = f2bf(a[j] - bf2f(hh));
        }
        aH[ks] = __builtin_bit_cast(bf16x8, h);
        aL[ks] = __builtin_bit_cast(bf16x8, lo);
      }
#pragma unroll
      for (int ct = 0; ct < 4; ++ct) {
        f32x4 acc = {0.f, 0.f, 0.f, 0.f};
#pragma unroll
        for (int ks = 0; ks < 4; ++ks) {
          bf16x8 sH = __builtin_bit_cast(bf16x8, sSfH[ks * 4 + ct][lane]);
          bf16x8 sL = __builtin_bit_cast(bf16x8, sSfL[ks * 4 + ct][lane]);
          acc = __builtin_amdgcn_mfma_f32_16x16x32_bf16(aH[ks], sH, acc, 0, 0, 0);
          acc = __builtin_amdgcn_mfma_f32_16x16x32_bf16(aL[ks], sH, acc, 0, 0, 0);
          acc = __builtin_amdgcn_mfma_f32_16x16x32_bf16(aH[ks], sL, acc, 0, 0, 0);
        }
        // C layout: col = lane&15, row = (lane>>4)*4 + reg  [verified m89/m91]
#pragma unroll
        for (int reg = 0; reg < 4; ++reg) {
          int orow = r0 + kg * 4 + reg;
          if (orow < SEQ) sBeh[orow][ct * 16 + fr] = acc[reg];
        }
      }
    }
  }
  __syncthreads();

  // ---- routing rounds (unchanged from R3, proven) ----
  for (int round = 0; round < NROUNDS; ++round) {
    // Phase A: masked softmax over l; wave w owns capsule k=w.
    {
      const int k = w;
      float v0 = sB[k][lane],       f0 = sMask[lane];
      float v1 = sB[k][lane + 64],  f1 = sMask[lane + 64];
      float v2 = sB[k][lane + 128], f2 = sMask[lane + 128];
      float v3 = 0.f, f3 = 0.f;
      if (lane < SEQ - 192) { v3 = sB[k][lane + 192]; f3 = sMask[lane + 192]; }
      float m = -3.402823466e38f;
      if (f0 > 0.f) m = fmaxf(m, v0);
      if (f1 > 0.f) m = fmaxf(m, v1);
      if (f2 > 0.f) m = fmaxf(m, v2);
      if (f3 > 0.f) m = fmaxf(m, v3);
#pragma unroll
      for (int off = 32; off >= 1; off >>= 1) m = fmaxf(m, __shfl_xor(m, off));
      float e0 = (f0 > 0.f) ? __expf(v0 - m) : 0.f;
      float e1 = (f1 > 0.f) ? __expf(v1 - m) : 0.f;
      float e2 = (f2 > 0.f) ? __expf(v2 - m) : 0.f;
      float e3 = (f3 > 0.f) ? __expf(v3 - m) : 0.f;
      float s = ((e0 + e1) + (e2 + e3));
#pragma unroll
      for (int off = 32; off >= 1; off >>= 1) s += __shfl_xor(s, off);
      float inv = (s > 0.f) ? (1.0f / s) : 0.f;
      sW[k][lane] = e0 * inv;
      sW[k][lane + 64] = e1 * inv;
      sW[k][lane + 128] = e2 * inv;
      if (lane < SEQ - 192) sW[k][lane + 192] = e3 * inv;
    }
    __syncthreads();

    // Phase B + squash: wave w owns k=w, lane owns d=lane.
    {
      float a0 = 0.f, a1 = 0.f, a2 = 0.f, a3 = 0.f;
#pragma unroll 2
      for (int l = 0; l < SEQ; l += 4) {
        a0 = fmaf(sW[w][l + 0], sBeh[l + 0][lane], a0);
        a1 = fmaf(sW[w][l + 1], sBeh[l + 1][lane], a1);
        a2 = fmaf(sW[w][l + 2], sBeh[l + 2][lane], a2);
        a3 = fmaf(sW[w][l + 3], sBeh[l + 3][lane], a3);
      }
      float v = (a0 + a1) + (a2 + a3);
      float q = v * v;
#pragma unroll
      for (int off = 32; off >= 1; off >>= 1) q += __shfl_xor(q, off);
      float n = sqrtf(q);
      float f = (q > 0.f) ? (q / ((1.0f + q) * n)) : 0.f;
      v *= f;
      sCaps[w][lane] = v;
      if (round == NROUNDS - 1)
        out[((size_t)b * NCAPS + w) * CDIM + lane] = v;
    }
    __syncthreads();

    // Phase D: B[k][l] += dot(caps[k], beh[l]).  k = t&7, l strided.
    if (round < NROUNDS - 1) {
      const int k = t & 7;
      float4 cp[16];
#pragma unroll
      for (int i = 0; i < 16; ++i) cp[i] = ld4(&sCaps[k][i * 4]);
      for (int oi = t; oi < NCAPS * SEQ; oi += NT) {
        int l = oi >> 3;
        float px = 0.f, py = 0.f, pz = 0.f, pw = 0.f;
#pragma unroll
        for (int i = 0; i < 16; ++i) {
          float4 b4 = ld4(&sBeh[l][i * 4]);
          px = fmaf(cp[i].x, b4.x, px);
          py = fmaf(cp[i].y, b4.y, py);
          pz = fmaf(cp[i].z, b4.z, pz);
          pw = fmaf(cp[i].w, b4.w, pw);
        }
        sB[k][l] += (px + py) + (pz + pw);
      }
      __syncthreads();
    } else {
      __syncthreads();
    }
  }
}

extern "C" void kernel_launch(void* const* d_in, const int* in_sizes, int n_in,
                              void* d_out, int out_size, void* d_ws, size_t ws_size,
                              hipStream_t stream) {
  const float* behaviors = (const float*)d_in[0];
  const unsigned char* maskraw = (const unsigned char*)d_in[1];
  const float* S = (const float*)d_in[2];
  const float* B0 = (const float*)d_in[3];
  float* out = (float*)d_out;
  const int B = in_sizes[0] / (SEQ * EMB);
  mie_kernel<<<dim3(B), dim3(NT), 0, stream>>>(behaviors, maskraw, S, B0, out);
}